// Round 1
// baseline (3787812.109 us; speedup 1.0000x reference)
//
#include <hip/hip_runtime.h>
#include <math.h>

// Persistent cooperative kernel for the sequential memory-bank RNN.
// 256 blocks x 256 threads, 3 grid barriers per timestep.
// Phase A: carry-dependent matvecs (ca,cm,wa,wm,rp,wp) -> chunked partials
// Phase B: redundant softmax finalize + fused mem read/update + r partials
// Phase C: W_r0/W_ra/W_rm matvecs -> carry partials (ping-pong banks)
// Carries are finalized lazily (relu(b + sum partials)) by consumers.

#define NB 256
#define NT 256
#define HH 2048
#define MM 512

#define SRC_HA 0
#define SRC_HM 1
#define SRC_H  2
#define SRC_R  3
#define SRC_XA 4
#define SRC_XM 5

struct Args {
  const float *xa, *xm;
  const float *W_ca, *b_ca, *W_cm, *b_cm, *W_wp, *b_wp, *W_wa, *b_wa;
  const float *W_wm, *b_wm, *W_rp, *b_rp, *W_r0, *b_r0, *W_ra, *b_ra, *W_rm, *b_rm;
  float *out;
  unsigned *bar;          // [0]=arrival counter, [32]=release flag (128B apart)
  float *mem;             // [512][2048] in-place updated
  float *ca_p, *cm_p;     // [32][2048]
  float *wa_p, *wm_p;     // [16][512]
  float *rp_p;            // [24][512]
  float *wp_l;            // [3] final gate logits (bias included)
  float *r_p;             // [32][2048]
  float *h1_p;            // [2][32][2048] ping-pong carry partials
  float *ha1_p, *hm1_p;   // [2][48][2048]
  int T;
};

// ---------------- grid barrier (generation counting, agent scope) ----------
__device__ __forceinline__ void gbar(unsigned* cnt, unsigned* flg, int gen) {
  __syncthreads();
  if (threadIdx.x == 0) {
    __threadfence();  // release: drain this block's stores device-wide
    unsigned arrived =
        __hip_atomic_fetch_add(cnt, 1u, __ATOMIC_ACQ_REL, __HIP_MEMORY_SCOPE_AGENT) + 1;
    if (arrived == (unsigned)gen * NB) {
      __hip_atomic_store(flg, (unsigned)gen, __ATOMIC_RELEASE, __HIP_MEMORY_SCOPE_AGENT);
    } else {
      while (__hip_atomic_load(flg, __ATOMIC_ACQUIRE, __HIP_MEMORY_SCOPE_AGENT) <
             (unsigned)gen) {
        __builtin_amdgcn_s_sleep(1);
      }
    }
    __threadfence();  // acquire: invalidate stale caches for whole CU
  }
  __syncthreads();
}

// ---------------- carry / input element fetch ------------------------------
__device__ __forceinline__ float fetch_src(const Args& a, int src, int off, int t) {
  switch (src) {
    case SRC_XA: return a.xa[(size_t)t * HH + off];
    case SRC_XM: return a.xm[(size_t)t * HH + off];
    case SRC_R: {
      float s = 0.f;
      const float* p = a.r_p + off;
      #pragma unroll
      for (int k = 0; k < 32; ++k) s += p[k * HH];
      return s;
    }
    case SRC_H: {
      if (t == 0) return 0.f;
      float s = a.b_r0[off];
      const float* p = a.h1_p + ((t - 1) & 1) * (32 * HH) + off;
      #pragma unroll
      for (int k = 0; k < 32; ++k) s += p[k * HH];
      return fmaxf(s, 0.f);
    }
    case SRC_HA: {
      if (t == 0) return 0.f;
      float s = a.b_ra[off];
      const float* p = a.ha1_p + ((t - 1) & 1) * (48 * HH) + off;
      #pragma unroll
      for (int k = 0; k < 48; ++k) s += p[k * HH];
      return fmaxf(s, 0.f);
    }
    default: {  // SRC_HM
      if (t == 0) return 0.f;
      float s = a.b_rm[off];
      const float* p = a.hm1_p + ((t - 1) & 1) * (48 * HH) + off;
      #pragma unroll
      for (int k = 0; k < 48; ++k) s += p[k * HH];
      return fmaxf(s, 0.f);
    }
  }
}

// stage n x-elements [i0, i0+n) into LDS; pack = segment sources (8b each)
__device__ __forceinline__ void stage_x(const Args& a, int pack, int i0, int n,
                                        int t, float* dst) {
  for (int idx = threadIdx.x; idx < n; idx += NT) {
    int gi = i0 + idx;
    int src = (pack >> ((gi >> 11) * 8)) & 0xff;
    dst[idx] = fetch_src(a, src, gi & (HH - 1), t);
  }
  __syncthreads();
}

// ---------------- partial matvecs ------------------------------------------
// fan_out 2048, 4 cols/thread (float4), n x-elements from LDS
__device__ __forceinline__ void mv_f4(const float* __restrict__ W,
                                      const float* __restrict__ xs,
                                      float* __restrict__ outp, int i0, int jt, int n) {
  const int j = jt * 1024 + threadIdx.x * 4;
  const float* wp = W + (size_t)i0 * HH + j;
  float ax = 0.f, ay = 0.f, az = 0.f, aw = 0.f;
  #pragma unroll 8
  for (int i = 0; i < n; ++i) {
    float xv = xs[i];
    float4 w = *(const float4*)wp;
    ax = fmaf(xv, w.x, ax);
    ay = fmaf(xv, w.y, ay);
    az = fmaf(xv, w.z, az);
    aw = fmaf(xv, w.w, aw);
    wp += HH;
  }
  float4 o; o.x = ax; o.y = ay; o.z = az; o.w = aw;
  *(float4*)(outp + j) = o;
}

// fan_out 512, 2 cols/thread (float2)
__device__ __forceinline__ void mv_f2(const float* __restrict__ W,
                                      const float* __restrict__ xs,
                                      float* __restrict__ outp, int i0, int n) {
  const int j = threadIdx.x * 2;
  const float* wp = W + (size_t)i0 * MM + j;
  float ax = 0.f, ay = 0.f;
  #pragma unroll 8
  for (int i = 0; i < n; ++i) {
    float xv = xs[i];
    float2 w = *(const float2*)wp;
    ax = fmaf(xv, w.x, ax);
    ay = fmaf(xv, w.y, ay);
    wp += MM;
  }
  float2 o; o.x = ax; o.y = ay;
  *(float2*)(outp + j) = o;
}

// ---------------- block reduction ------------------------------------------
__device__ __forceinline__ float bred(float v, bool domax, float* red) {
  #pragma unroll
  for (int o = 32; o > 0; o >>= 1) {
    float u = __shfl_xor(v, o, 64);
    v = domax ? fmaxf(v, u) : (v + u);
  }
  const int w = threadIdx.x >> 6;
  if ((threadIdx.x & 63) == 0) red[w] = v;
  __syncthreads();
  float r = red[0];
  #pragma unroll
  for (int i = 1; i < NT / 64; ++i) r = domax ? fmaxf(r, red[i]) : (r + red[i]);
  __syncthreads();
  return r;
}

// sm[512] := scale * softmax(bias + sum_k part[k][:])
__device__ void softmax512(float* sm, const float* __restrict__ part, int nk,
                           const float* __restrict__ bias, float scale, float* red) {
  const int tid = threadIdx.x;
  for (int m = tid; m < MM; m += NT) {
    float s = bias[m];
    for (int k = 0; k < nk; ++k) s += part[k * MM + m];
    sm[m] = s;
  }
  __syncthreads();
  float l0 = sm[tid], l1 = sm[tid + NT];
  float gm = bred(fmaxf(l0, l1), true, red);
  float e0 = expf(l0 - gm), e1 = expf(l1 - gm);
  float gs = bred(e0 + e1, false, red);
  float inv = scale / gs;
  sm[tid] = e0 * inv;
  sm[tid + NT] = e1 * inv;
  __syncthreads();
}

// ---------------- the persistent kernel ------------------------------------
__global__ void __launch_bounds__(NT, 1) memram(Args a) {
  const int tid = threadIdx.x;
  const int bid = blockIdx.x;
  __shared__ float s_x[512];
  __shared__ float s_ar[512];
  __shared__ float s_wa[512];
  __shared__ float s_wm[512];
  __shared__ float s_red[8];

  unsigned* cnt = a.bar;
  unsigned* flg = a.bar + 32;
  int gen = 0;

  for (int t = 0;; ++t) {
    // ================= PHASE A =================
    // finalize + emit previous step's hidden output
    if (t > 0 && bid == 185) {
      const float* p = a.h1_p + ((t - 1) & 1) * (32 * HH);
      float* o = a.out + (size_t)(t - 1) * HH;
      for (int c = tid; c < HH; c += NT) {
        float s = a.b_r0[c];
        #pragma unroll
        for (int k = 0; k < 32; ++k) s += p[k * HH + c];
        o[c] = fmaxf(s, 0.f);
      }
    }
    if (t < a.T) {
      if (bid < 128) {                       // CA (0..63) / CM (64..127)
        const bool cm = bid >= 64;
        const int id = bid & 63;
        const int jt = id >> 5, kc = id & 31;
        const int i0 = kc * 128;
        const int pack = cm ? (SRC_HM | (SRC_XM << 8)) : (SRC_HA | (SRC_XA << 8));
        stage_x(a, pack, i0, 128, t, s_x);
        mv_f4(cm ? a.W_cm : a.W_ca, s_x, (cm ? a.cm_p : a.ca_p) + kc * HH, i0, jt, 128);
      } else if (bid < 160) {                // WA (128..143) / WM (144..159)
        const bool wm = bid >= 144;
        const int kc = bid - (wm ? 144 : 128);
        const int i0 = kc * 256;
        const int pack = wm ? (SRC_HM | (SRC_XM << 8)) : (SRC_HA | (SRC_XA << 8));
        stage_x(a, pack, i0, 256, t, s_x);
        mv_f2(wm ? a.W_wm : a.W_wa, s_x, (wm ? a.wm_p : a.wa_p) + kc * MM, i0, 256);
      } else if (bid < 184) {                // RP (160..183)
        const int kc = bid - 160;
        const int i0 = kc * 256;
        const int pack = SRC_HA | (SRC_HM << 8) | (SRC_H << 16);
        stage_x(a, pack, i0, 256, t, s_x);
        mv_f2(a.W_rp, s_x, a.rp_p + kc * MM, i0, 256);
      } else if (bid == 184) {               // WP (gate logits, fan_out 3)
        const int pack = SRC_HA | (SRC_HM << 8) | (SRC_H << 16);
        float a0 = 0.f, a1 = 0.f, a2 = 0.f;
        for (int i = tid; i < 3 * HH; i += NT) {
          int src = (pack >> ((i >> 11) * 8)) & 0xff;
          float xv = fetch_src(a, src, i & (HH - 1), t);
          a0 = fmaf(xv, a.W_wp[i * 3 + 0], a0);
          a1 = fmaf(xv, a.W_wp[i * 3 + 1], a1);
          a2 = fmaf(xv, a.W_wp[i * 3 + 2], a2);
        }
        a0 = bred(a0, false, s_red);
        a1 = bred(a1, false, s_red);
        a2 = bred(a2, false, s_red);
        if (tid == 0) {
          a.wp_l[0] = a0 + a.b_wp[0];
          a.wp_l[1] = a1 + a.b_wp[1];
          a.wp_l[2] = a2 + a.b_wp[2];
        }
      }
    }
    if (t == a.T) break;
    gbar(cnt, flg, ++gen);

    // ================= PHASE B =================
    if (bid < 64) {
      const int rc = bid >> 1, ct = bid & 1;
      float w0 = a.wp_l[0], w1 = a.wp_l[1], w2 = a.wp_l[2];
      float mw = fmaxf(fmaxf(w0, w1), w2);
      float e0 = expf(w0 - mw), e1 = expf(w1 - mw), e2 = expf(w2 - mw);
      float inv3 = 1.0f / (e0 + e1 + e2);
      float aw0 = e0 * inv3, aw1 = e1 * inv3, aw2 = e2 * inv3;
      softmax512(s_ar, a.rp_p, 24, a.b_rp, 1.0f, s_red);
      softmax512(s_wa, a.wa_p, 16, a.b_wa, aw1, s_red);
      softmax512(s_wm, a.wm_p, 16, a.b_wm, aw2, s_red);
      const int c = ct * 1024 + tid * 4;
      float4 ca4, cm4;
      {
        float4 s = *(const float4*)(a.b_ca + c);
        #pragma unroll
        for (int k = 0; k < 32; ++k) {
          float4 p = *(const float4*)(a.ca_p + k * HH + c);
          s.x += p.x; s.y += p.y; s.z += p.z; s.w += p.w;
        }
        ca4.x = fmaxf(s.x, 0.f); ca4.y = fmaxf(s.y, 0.f);
        ca4.z = fmaxf(s.z, 0.f); ca4.w = fmaxf(s.w, 0.f);
      }
      {
        float4 s = *(const float4*)(a.b_cm + c);
        #pragma unroll
        for (int k = 0; k < 32; ++k) {
          float4 p = *(const float4*)(a.cm_p + k * HH + c);
          s.x += p.x; s.y += p.y; s.z += p.z; s.w += p.w;
        }
        cm4.x = fmaxf(s.x, 0.f); cm4.y = fmaxf(s.y, 0.f);
        cm4.z = fmaxf(s.z, 0.f); cm4.w = fmaxf(s.w, 0.f);
      }
      float rx = 0.f, ry = 0.f, rz = 0.f, rw = 0.f;
      float* memp = a.mem + (size_t)rc * 16 * HH + c;
      #pragma unroll 4
      for (int i = 0; i < 16; ++i) {
        const int m = rc * 16 + i;
        float4 mv;
        if (t == 0) { mv.x = 0.f; mv.y = 0.f; mv.z = 0.f; mv.w = 0.f; }
        else mv = *(const float4*)memp;
        const float arm = s_ar[m], wam = s_wa[m], wmm = s_wm[m];
        rx = fmaf(arm, mv.x, rx); ry = fmaf(arm, mv.y, ry);
        rz = fmaf(arm, mv.z, rz); rw = fmaf(arm, mv.w, rw);
        float4 nv;
        nv.x = aw0 * mv.x + wam * ca4.x + wmm * cm4.x;
        nv.y = aw0 * mv.y + wam * ca4.y + wmm * cm4.y;
        nv.z = aw0 * mv.z + wam * ca4.z + wmm * cm4.z;
        nv.w = aw0 * mv.w + wam * ca4.w + wmm * cm4.w;
        *(float4*)memp = nv;
        memp += HH;
      }
      float4 r4; r4.x = rx; r4.y = ry; r4.z = rz; r4.w = rw;
      *(float4*)(a.r_p + rc * HH + c) = r4;
    }
    gbar(cnt, flg, ++gen);

    // ================= PHASE C =================
    {
      const float* W;
      float* outp;
      int pack, kc, jt;
      if (bid < 64) {                        // h1 = relu([r,h] W_r0 + b_r0)
        jt = bid >> 5; kc = bid & 31;
        W = a.W_r0;
        outp = a.h1_p + (t & 1) * (32 * HH) + kc * HH;
        pack = SRC_R | (SRC_H << 8);
      } else if (bid < 160) {                // ha1 = relu([xa,r,ha] W_ra + b_ra)
        const int r = bid - 64;
        jt = r / 48; kc = r % 48;
        W = a.W_ra;
        outp = a.ha1_p + (t & 1) * (48 * HH) + kc * HH;
        pack = SRC_XA | (SRC_R << 8) | (SRC_HA << 16);
      } else {                               // hm1 = relu([xm,r,hm] W_rm + b_rm)
        const int r = bid - 160;
        jt = r / 48; kc = r % 48;
        W = a.W_rm;
        outp = a.hm1_p + (t & 1) * (48 * HH) + kc * HH;
        pack = SRC_XM | (SRC_R << 8) | (SRC_HM << 16);
      }
      const int i0 = kc * 128;
      stage_x(a, pack, i0, 128, t, s_x);
      mv_f4(W, s_x, outp, i0, jt, 128);
    }
    gbar(cnt, flg, ++gen);
  }
}

// ---------------- host side ------------------------------------------------
extern "C" void kernel_launch(void* const* d_in, const int* in_sizes, int n_in,
                              void* d_out, int out_size, void* d_ws, size_t ws_size,
                              hipStream_t stream) {
  Args a;
  a.xa   = (const float*)d_in[0];
  a.xm   = (const float*)d_in[1];
  a.W_ca = (const float*)d_in[2];  a.b_ca = (const float*)d_in[3];
  a.W_cm = (const float*)d_in[4];  a.b_cm = (const float*)d_in[5];
  a.W_wp = (const float*)d_in[6];  a.b_wp = (const float*)d_in[7];
  a.W_wa = (const float*)d_in[8];  a.b_wa = (const float*)d_in[9];
  a.W_wm = (const float*)d_in[10]; a.b_wm = (const float*)d_in[11];
  a.W_rp = (const float*)d_in[12]; a.b_rp = (const float*)d_in[13];
  a.W_r0 = (const float*)d_in[14]; a.b_r0 = (const float*)d_in[15];
  a.W_ra = (const float*)d_in[16]; a.b_ra = (const float*)d_in[17];
  a.W_rm = (const float*)d_in[18]; a.b_rm = (const float*)d_in[19];
  a.out  = (float*)d_out;
  a.T    = out_size / HH;

  char* w = (char*)d_ws;
  size_t off = 0;
  auto take = [&](size_t bytes) -> char* {
    char* p = w + off;
    off += (bytes + 255) & ~(size_t)255;
    return p;
  };
  a.bar   = (unsigned*)take(256);
  a.mem   = (float*)take((size_t)MM * HH * 4);
  a.ca_p  = (float*)take((size_t)32 * HH * 4);
  a.cm_p  = (float*)take((size_t)32 * HH * 4);
  a.wa_p  = (float*)take((size_t)16 * MM * 4);
  a.wm_p  = (float*)take((size_t)16 * MM * 4);
  a.rp_p  = (float*)take((size_t)24 * MM * 4);
  a.wp_l  = (float*)take(256);
  a.r_p   = (float*)take((size_t)32 * HH * 4);
  a.h1_p  = (float*)take((size_t)2 * 32 * HH * 4);
  a.ha1_p = (float*)take((size_t)2 * 48 * HH * 4);
  a.hm1_p = (float*)take((size_t)2 * 48 * HH * 4);
  (void)ws_size;  // requires ~7.2 MB of workspace
  (void)in_sizes; (void)n_in;

  // reset barrier state (graph-capturable)
  hipMemsetAsync(d_ws, 0, 256, stream);

  void* kargs[] = { &a };
  hipError_t err = hipLaunchCooperativeKernel((const void*)memram, dim3(NB), dim3(NT),
                                              kargs, 0, stream);
  if (err != hipSuccess) {
    // fallback: plain launch (256 blocks on 256 CUs are co-resident in practice)
    hipLaunchKernelGGL(memram, dim3(NB), dim3(NT), 0, stream, a);
  }
}